// Round 3
// baseline (2816.924 us; speedup 1.0000x reference)
//
#include <hip/hip_runtime.h>

#define TT 256
#define BB 32
#define HH 512
#define EE 512
#define GG 2048
#define MM 8192
#define NWG 32   // workgroups per direction in lstm_rec

typedef __attribute__((ext_vector_type(8))) short bf16x8;
typedef __attribute__((ext_vector_type(4))) float f32x4;
typedef __attribute__((ext_vector_type(4))) unsigned short us4;
typedef unsigned long long ull;

__device__ inline float b2f(unsigned short u) {
    union { unsigned int i; float f; } v; v.i = ((unsigned int)u) << 16; return v.f;
}
__device__ inline unsigned short f2b(float f) {
    union { float f; unsigned int i; } v; v.f = f;
    unsigned int x = v.i;
    return (unsigned short)((x + 0x7FFFu + ((x >> 16) & 1u)) >> 16);
}
__device__ inline float sigm(float x) { return 1.f / (1.f + __expf(-x)); }
__device__ inline float tanh_f(float x) {
    float ax = fminf(fabsf(x), 12.f);
    float e = __expf(2.f * ax);
    float r = (e - 1.f) / (e + 1.f);
    return x < 0.f ? -r : r;
}

#define AGLD(p) __hip_atomic_load((p), __ATOMIC_RELAXED, __HIP_MEMORY_SCOPE_AGENT)

// pair-flag readiness: 8B load covers flg[2p] and flg[2p+1]
__device__ inline bool prdy(ull f, unsigned int tgt) {
    return ((unsigned int)f >= tgt) && ((unsigned int)(f >> 32) >= tgt);
}

// ---------------- prep + embed fused ----------------
__global__ void prep_embed_k(const int* __restrict__ ids, const float* __restrict__ emb,
                             const float* __restrict__ wihf, const float* __restrict__ whhf,
                             const float* __restrict__ wihb, const float* __restrict__ whhb,
                             const float* __restrict__ bihf, const float* __restrict__ bhhf,
                             const float* __restrict__ bihb, const float* __restrict__ bhhb,
                             unsigned short* __restrict__ xb, unsigned short* __restrict__ wih,
                             unsigned short* __restrict__ whh, float* __restrict__ bias)
{
    int v = blockIdx.x * 256 + threadIdx.x;   // 0..1048575
    {   // embedding: x[row][col4..col4+3]
        int row = v >> 7;
        int col4 = (v & 127) * 4;
        int id = ids[row];
        float4 e;
        if (id != 0) e = *(const float4*)(emb + (size_t)id * 512 + col4);
        else { e.x = 0.f; e.y = 0.f; e.z = 0.f; e.w = 0.f; }
        us4 o; o.x = f2b(e.x); o.y = f2b(e.y); o.z = f2b(e.z); o.w = f2b(e.w);
        *(us4*)(xb + (size_t)row * 512 + col4) = o;
    }
    if (v < 262144) {   // weight convert + bias sums
        float4 a; us4 o;
        a = ((const float4*)wihf)[v];
        o.x = f2b(a.x); o.y = f2b(a.y); o.z = f2b(a.z); o.w = f2b(a.w);
        *(us4*)(wih + (size_t)v * 4) = o;
        a = ((const float4*)whhf)[v];
        o.x = f2b(a.x); o.y = f2b(a.y); o.z = f2b(a.z); o.w = f2b(a.w);
        *(us4*)(whh + (size_t)v * 4) = o;
        a = ((const float4*)wihb)[v];
        o.x = f2b(a.x); o.y = f2b(a.y); o.z = f2b(a.z); o.w = f2b(a.w);
        *(us4*)(wih + 1048576 + (size_t)v * 4) = o;
        a = ((const float4*)whhb)[v];
        o.x = f2b(a.x); o.y = f2b(a.y); o.z = f2b(a.z); o.w = f2b(a.w);
        *(us4*)(whh + 1048576 + (size_t)v * 4) = o;
        if (v < 2048)      bias[v] = bihf[v] + bhhf[v];
        else if (v < 4096) bias[v] = bihb[v - 2048] + bhhb[v - 2048];
    }
}

// ---------------- persistent bidirectional LSTM, as-arrives h consumption ----------------
// grid 64: dir = bx>>5, wg = bx&31 owns hidden cols [wg*16, wg*16+16). 1 WG/CU.
// The [wait-all-flags -> bulk gather -> LDS -> h-MFMA] block is replaced by a per-wave
// depth-8 software pipeline over the 16 producer PAIRS (K=32 slices):
//   pre-issued pair-flag samples -> (spin only if stale) -> direct agent loads of the
//   A-fragments from h_all -> MFMA. No hbuf, no barriers in the h path; per-WG rotated
//   processing order ((i+wg)&15, baked into wfr) de-correlates straggler impact.
__global__ __launch_bounds__(256, 1) void lstm_rec(const unsigned short* __restrict__ whh,
                                                   const unsigned short* __restrict__ wih,
                                                   const unsigned short* __restrict__ xb,
                                                   const float* __restrict__ bias,
                                                   unsigned short* __restrict__ h_all,
                                                   unsigned int* __restrict__ cnt)
{
    __shared__ unsigned short xbuf[2][32][520];   // x_t staging, double-buffered
    __shared__ float gbuf[4][32][16];             // gate pre-activations

    const int bx = blockIdx.x;
    const int dir = bx >> 5;
    const int wg = bx & 31;
    const int js = wg * 16;
    const int tid = threadIdx.x;
    const int wave = tid >> 6, lane = tid & 63;
    const int quad = lane >> 4, r16 = lane & 15;
    const int colw = wave * 512 + js + r16;       // gate-row in whh/wih

    // B-fragments: w_hh slices stored in ROTATED pair order (i -> pair (i+wg)&15)
    // so the pipeline loop indexes wfr[] statically; w_ih in natural order.
    bf16x8 wfr[16], xfr[16];
    {
        const unsigned short* wrow = whh + (size_t)dir * GG * HH + (size_t)colw * 512;
        const unsigned short* xrow = wih + (size_t)dir * GG * EE + (size_t)colw * 512;
#pragma unroll
        for (int i = 0; i < 16; ++i) {
            wfr[i] = *(const bf16x8*)(wrow + ((i + wg) & 15) * 32 + quad * 8);
            xfr[i] = *(const bf16x8*)(xrow + i * 32 + quad * 8);
        }
    }
    const float bsw = bias[dir * GG + colw];

    // cell state in registers: thread owns (b = tid>>3, j = js + 2*(tid&7) + {0,1})
    const int cb = tid >> 3, cj = (tid & 7) * 2;
    float cr0 = 0.f, cr1 = 0.f;

    unsigned short* hd = h_all + (size_t)dir * TT * BB * HH;
    unsigned int* flg = cnt + dir * NWG;
    const ull* xbsrc = (const ull*)xb;            // 128 ull per 512-col row

    // prologue: stage x for the first step into xbuf[0]
    {
        const int te0 = dir ? (TT - 1) : 0;
#pragma unroll
        for (int i = 0; i < 16; ++i) {
            int v = tid + i * 256;
            int row = v >> 7, wi = v & 127;
            ull xv = xbsrc[((size_t)(row << 8) + te0) * 128 + wi];
            *(ull*)&xbuf[0][row][wi * 4] = xv;
        }
    }
    __syncthreads();
    int buf = 0;

    for (int t = 0; t < TT; ++t) {
        const int te = dir ? (TT - 1 - t) : t;
        const unsigned int tgt = (unsigned int)t;

        // pre-issue pair-flag samples for the first 8 pipeline stages
        // (issued BEFORE xpre so waiting on them does not drain the x loads)
        ull pfl[16];
        if (t > 0) {
#pragma unroll
            for (int i = 0; i < 8; ++i)
                pfl[i] = AGLD((const ull*)&flg[2 * ((i + wg) & 15)]);
        }

        // issue next step's x prefetch (held in regs; written to LDS at step end)
        ull xpre[16];
        if (t + 1 < TT) {
            const int tn = dir ? (te - 1) : (te + 1);
#pragma unroll
            for (int i = 0; i < 16; ++i) {
                int v = tid + i * 256;
                int row = v >> 7, wi = v & 127;
                xpre[i] = xbsrc[((size_t)(row << 8) + tn) * 128 + wi];
            }
        }

        // ---- x-MFMA: acc := x_t @ Wih^T  (fills flag-propagation time) ----
        f32x4 alo = {0.f, 0.f, 0.f, 0.f}, ahi = {0.f, 0.f, 0.f, 0.f};
#pragma unroll
        for (int kc = 0; kc < 16; ++kc) {
            const int ko = kc * 32 + quad * 8;
            bf16x8 aflo = *(const bf16x8*)&xbuf[buf][r16][ko];
            bf16x8 afhi = *(const bf16x8*)&xbuf[buf][16 + r16][ko];
            alo = __builtin_amdgcn_mfma_f32_16x16x32_bf16(aflo, xfr[kc], alo, 0, 0, 0);
            ahi = __builtin_amdgcn_mfma_f32_16x16x32_bf16(afhi, xfr[kc], ahi, 0, 0, 0);
        }

        // ---- h-phase: per-wave as-arrives pipelined consumption of 16 pairs ----
        if (t > 0) {
            const int tp = dir ? (te + 1) : (te - 1);
            const unsigned short* hsrc = hd + (size_t)tp * BB * HH;
            const ull* hlo = (const ull*)hsrc + (size_t)r16 * 128 + quad * 2;
            const ull* hhi = (const ull*)hsrc + (size_t)(16 + r16) * 128 + quad * 2;
            ull av[8][4];   // depth-8 slot ring: [slot]{lo0,lo1,hi0,hi1}

            // FILL: issue A-loads for stages 0..7; refresh flag samples for 8..15
#pragma unroll
            for (int i = 0; i < 8; ++i) {
                const int p = (i + wg) & 15;
                ull f = pfl[i];
                while (!prdy(f, tgt))
                    f = AGLD((const ull*)&flg[2 * p]);
                asm volatile("" ::: "memory");   // no hoist of data loads above flag
                const ull* pl = hlo + (size_t)p * 8;
                const ull* ph = hhi + (size_t)p * 8;
                av[i][0] = AGLD(pl);
                av[i][1] = AGLD(pl + 1);
                av[i][2] = AGLD(ph);
                av[i][3] = AGLD(ph + 1);
                pfl[i + 8] = AGLD((const ull*)&flg[2 * ((i + 8 + wg) & 15)]);
            }
            // MAIN: MFMA stage i from slot i&7; refill slot with stage i+8
#pragma unroll
            for (int i = 0; i < 16; ++i) {
                const int s = i & 7;
                union { ull u[2]; bf16x8 v; } fl, fh;
                fl.u[0] = av[s][0]; fl.u[1] = av[s][1];
                fh.u[0] = av[s][2]; fh.u[1] = av[s][3];
                alo = __builtin_amdgcn_mfma_f32_16x16x32_bf16(fl.v, wfr[i], alo, 0, 0, 0);
                ahi = __builtin_amdgcn_mfma_f32_16x16x32_bf16(fh.v, wfr[i], ahi, 0, 0, 0);
                if (i < 8) {
                    const int p = (i + 8 + wg) & 15;
                    ull f = pfl[i + 8];
                    while (!prdy(f, tgt))
                        f = AGLD((const ull*)&flg[2 * p]);
                    asm volatile("" ::: "memory");
                    const ull* pl = hlo + (size_t)p * 8;
                    const ull* ph = hhi + (size_t)p * 8;
                    av[s][0] = AGLD(pl);
                    av[s][1] = AGLD(pl + 1);
                    av[s][2] = AGLD(ph);
                    av[s][3] = AGLD(ph + 1);
                }
            }
        }

#pragma unroll
        for (int r = 0; r < 4; ++r) {
            gbuf[wave][quad * 4 + r][r16]      = alo[r] + bsw;
            gbuf[wave][16 + quad * 4 + r][r16] = ahi[r] + bsw;
        }
        __syncthreads();   // B2: gbuf ready

        // nonlinearity: thread owns (cb, cj) and (cb, cj+1)
        {
            float2 iv = *(const float2*)&gbuf[0][cb][cj];
            float2 fv = *(const float2*)&gbuf[1][cb][cj];
            float2 gv = *(const float2*)&gbuf[2][cb][cj];
            float2 ov = *(const float2*)&gbuf[3][cb][cj];
            cr0 = sigm(fv.x) * cr0 + sigm(iv.x) * tanh_f(gv.x);
            cr1 = sigm(fv.y) * cr1 + sigm(iv.y) * tanh_f(gv.y);
            float h0 = sigm(ov.x) * tanh_f(cr0);
            float h1 = sigm(ov.y) * tanh_f(cr1);
            unsigned int packed = (unsigned int)f2b(h0) | ((unsigned int)f2b(h1) << 16);
            unsigned int* hp = (unsigned int*)(hd + (size_t)te * BB * HH + cb * 512 + js + cj);
            __hip_atomic_store(hp, packed, __ATOMIC_RELAXED, __HIP_MEMORY_SCOPE_AGENT);
        }

        // write prefetched x into the other buffer (overlaps h-store drain)
        if (t + 1 < TT) {
#pragma unroll
            for (int i = 0; i < 16; ++i) {
                int v = tid + i * 256;
                *(ull*)&xbuf[buf ^ 1][v >> 7][(v & 127) * 4] = xpre[i];
            }
            buf ^= 1;
        }
        __syncthreads();   // B3: vmcnt drained (h stores acked) + xbuf[new] ready
        if (tid == 0)
            __hip_atomic_store(&flg[wg], (unsigned int)(t + 1),
                               __ATOMIC_RELAXED, __HIP_MEMORY_SCOPE_AGENT);
    }
}

// ---------------- classifier: logits = [hf|hb] @ cls_w^T + cls_b ----------------
__global__ __launch_bounds__(256) void logits_k(const unsigned short* __restrict__ h_all,
                                                const float* __restrict__ clsw,
                                                const float* __restrict__ clsb,
                                                float* __restrict__ logits)
{
    const int tid = threadIdx.x;
    const int wave = tid >> 6, lane = tid & 63;
    const int wgid = blockIdx.x * 4 + wave;    // 0..1023

    unsigned int wreg[9][8];
#pragma unroll
    for (int c = 0; c < 9; ++c)
#pragma unroll
        for (int q = 0; q < 8; ++q) {
            float w0 = clsw[c * 1024 + (2 * q) * 64 + lane];
            float w1 = clsw[c * 1024 + (2 * q + 1) * 64 + lane];
            wreg[c][q] = (unsigned int)f2b(w0) | ((unsigned int)f2b(w1) << 16);
        }

    const unsigned short* hfb = h_all;
    const unsigned short* hbb = h_all + (size_t)TT * BB * HH;

    for (int i = 0; i < 8; ++i) {
        int m = wgid * 8 + i;                  // m = b*256 + t
        int b = m >> 8, t = m & 255;
        const unsigned short* hf = hfb + ((size_t)t * BB + b) * HH;
        const unsigned short* hb = hbb + ((size_t)t * BB + b) * HH;
        float acc[9];
#pragma unroll
        for (int c = 0; c < 9; ++c) acc[c] = 0.f;
#pragma unroll
        for (int u = 0; u < 16; ++u) {
            const unsigned short* src = (u < 8) ? (hf + u * 64) : (hb + (u - 8) * 64);
            float hv = b2f(src[lane]);
#pragma unroll
            for (int c = 0; c < 9; ++c) {
                unsigned short wv = (u & 1) ? (unsigned short)(wreg[c][u >> 1] >> 16)
                                            : (unsigned short)(wreg[c][u >> 1] & 0xFFFFu);
                acc[c] += hv * b2f(wv);
            }
        }
#pragma unroll
        for (int c = 0; c < 9; ++c) {
            float s = acc[c];
            for (int off = 32; off > 0; off >>= 1) s += __shfl_down(s, off);
            if (lane == 0) logits[(size_t)m * 9 + c] = s + clsb[c];
        }
    }
}

// ---------------- CRF log-likelihood per sequence ----------------
__global__ void crf_k(const float* __restrict__ logits, const int* __restrict__ label,
                      const float* __restrict__ startp, const float* __restrict__ endp,
                      const float* __restrict__ trans, float* __restrict__ llh)
{
    const int b = blockIdx.x;
    const int lane = threadIdx.x;   // 64
    __shared__ float tr[81];
    __shared__ float alpha[9];
    __shared__ int tags[TT];
    for (int v = lane; v < 81; v += 64) tr[v] = trans[v];
    for (int v = lane; v < TT; v += 64) tags[v] = label[b * TT + v];
    __syncthreads();
    const float* lg = logits + (size_t)b * TT * 9;

    float part = 0.f; int mcnt = 0;
    for (int t = lane; t < TT; t += 64) {
        int tg = tags[t];
        bool m = tg > -1;
        if (m) mcnt++;
        if (t == 0)      part += startp[tg] + lg[tg];
        else if (m)      part += lg[t * 9 + tg] + tr[tags[t - 1] * 9 + tg];
    }
    for (int off = 32; off > 0; off >>= 1) {
        part += __shfl_down(part, off);
        mcnt += __shfl_down(mcnt, off);
    }
    part = __shfl(part, 0);
    mcnt = __shfl(mcnt, 0);
    float num = part + endp[tags[mcnt - 1]];

    if (lane < 9) alpha[lane] = startp[lane] + lg[lane];
    __syncthreads();
    for (int t = 1; t < TT; ++t) {
        float nxt = 0.f;
        if (lane < 9) {
            float mx = -1e30f;
#pragma unroll
            for (int c1 = 0; c1 < 9; ++c1) mx = fmaxf(mx, alpha[c1] + tr[c1 * 9 + lane]);
            float s = 0.f;
#pragma unroll
            for (int c1 = 0; c1 < 9; ++c1) s += __expf(alpha[c1] + tr[c1 * 9 + lane] - mx);
            nxt = mx + __logf(s) + lg[t * 9 + lane];
            if (tags[t] <= -1) nxt = alpha[lane];
        }
        __syncthreads();
        if (lane < 9) alpha[lane] = nxt;
        __syncthreads();
    }
    if (lane == 0) {
        float mx = -1e30f;
#pragma unroll
        for (int c = 0; c < 9; ++c) mx = fmaxf(mx, alpha[c] + endp[c]);
        float s = 0.f;
#pragma unroll
        for (int c = 0; c < 9; ++c) s += __expf(alpha[c] + endp[c] - mx);
        llh[b] = num - (mx + __logf(s));
    }
}

__global__ void fin_k(const float* __restrict__ llh, float* __restrict__ out)
{
    int lane = threadIdx.x;
    float v = (lane < 32) ? llh[lane] : 0.f;
    for (int off = 32; off > 0; off >>= 1) v += __shfl_down(v, off);
    if (lane == 0) out[0] = -v * (1.f / 32.f);
}

// ---------------- launch ----------------
extern "C" void kernel_launch(void* const* d_in, const int* in_sizes, int n_in,
                              void* d_out, int out_size, void* d_ws, size_t ws_size,
                              hipStream_t stream)
{
    const int*   ids   = (const int*)  d_in[0];
    const int*   label = (const int*)  d_in[1];
    const float* emb   = (const float*)d_in[2];
    const float* wihf  = (const float*)d_in[3];
    const float* whhf  = (const float*)d_in[4];
    const float* bihf  = (const float*)d_in[5];
    const float* bihf2 = 0; (void)bihf2;
    const float* bhhf  = (const float*)d_in[6];
    const float* wihb  = (const float*)d_in[7];
    const float* whhb  = (const float*)d_in[8];
    const float* bihb  = (const float*)d_in[9];
    const float* bhhb  = (const float*)d_in[10];
    const float* clsw  = (const float*)d_in[11];
    const float* clsb  = (const float*)d_in[12];
    const float* stp   = (const float*)d_in[13];
    const float* enp   = (const float*)d_in[14];
    const float* trp   = (const float*)d_in[15];

    char* ws = (char*)d_ws;
    unsigned short* xb   = (unsigned short*)(ws + 0);           //  8 MB  [8192][512] bf16
    unsigned short* wih  = (unsigned short*)(ws + 8388608);     //  4 MB  [2][2048][512]
    unsigned short* whh  = (unsigned short*)(ws + 12582912);    //  4 MB  [2][2048][512]
    float*          bias = (float*)(ws + 16777216);             // 16 KB  [2][2048]
    unsigned short* hall = (unsigned short*)(ws + 16793600);    // 16 MB  [2][256][32][512]
    float*          lgt  = (float*)(ws + 33570816);             // 288 KB [8192][9]
    float*          llh  = (float*)(ws + 33865728);             // 128 B
    unsigned int*   cnt  = (unsigned int*)(ws + 33865856);      // flags [2][32]

    hipMemsetAsync(cnt, 0, 256, stream);
    prep_embed_k<<<4096, 256, 0, stream>>>(ids, emb, wihf, whhf, wihb, whhb,
                                           bihf, bhhf, bihb, bhhb, xb, wih, whh, bias);
    lstm_rec<<<64, 256, 0, stream>>>(whh, wih, xb, bias, hall, cnt);
    logits_k<<<256, 256, 0, stream>>>(hall, clsw, clsb, lgt);
    crf_k<<<32, 64, 0, stream>>>(lgt, label, stp, enp, trp, llh);
    fin_k<<<1, 64, 0, stream>>>(llh, (float*)d_out);
}

// Round 5
// 1651.064 us; speedup vs baseline: 1.7061x; 1.7061x over previous
//
#include <hip/hip_runtime.h>

#define TT 256
#define BB 32
#define HH 512
#define EE 512
#define GG 2048
#define MM 8192
#define NWG 32   // workgroups per direction in lstm_rec

typedef __attribute__((ext_vector_type(8))) short bf16x8;
typedef __attribute__((ext_vector_type(4))) float f32x4;
typedef __attribute__((ext_vector_type(4))) unsigned short us4;
typedef unsigned long long ull;

__device__ inline float b2f(unsigned short u) {
    union { unsigned int i; float f; } v; v.i = ((unsigned int)u) << 16; return v.f;
}
__device__ inline unsigned short f2b(float f) {
    union { float f; unsigned int i; } v; v.f = f;
    unsigned int x = v.i;
    return (unsigned short)((x + 0x7FFFu + ((x >> 16) & 1u)) >> 16);
}
__device__ inline float sigm(float x) { return 1.f / (1.f + __expf(-x)); }
__device__ inline float tanh_f(float x) {
    float ax = fminf(fabsf(x), 12.f);
    float e = __expf(2.f * ax);
    float r = (e - 1.f) / (e + 1.f);
    return x < 0.f ? -r : r;
}

#define AGLD(p) __hip_atomic_load((p), __ATOMIC_RELAXED, __HIP_MEMORY_SCOPE_AGENT)
#define ASTD(p, v) __hip_atomic_store((p), (v), __ATOMIC_RELAXED, __HIP_MEMORY_SCOPE_AGENT)

// ---------------- prep + embed fused ----------------
__global__ void prep_embed_k(const int* __restrict__ ids, const float* __restrict__ emb,
                             const float* __restrict__ wihf, const float* __restrict__ whhf,
                             const float* __restrict__ wihb, const float* __restrict__ whhb,
                             const float* __restrict__ bihf, const float* __restrict__ bhhf,
                             const float* __restrict__ bihb, const float* __restrict__ bhhb,
                             unsigned short* __restrict__ xb, unsigned short* __restrict__ wih,
                             unsigned short* __restrict__ whh, float* __restrict__ bias)
{
    int v = blockIdx.x * 256 + threadIdx.x;   // 0..1048575
    {   // embedding: x[row][col4..col4+3]
        int row = v >> 7;
        int col4 = (v & 127) * 4;
        int id = ids[row];
        float4 e;
        if (id != 0) e = *(const float4*)(emb + (size_t)id * 512 + col4);
        else { e.x = 0.f; e.y = 0.f; e.z = 0.f; e.w = 0.f; }
        us4 o; o.x = f2b(e.x); o.y = f2b(e.y); o.z = f2b(e.z); o.w = f2b(e.w);
        *(us4*)(xb + (size_t)row * 512 + col4) = o;
    }
    if (v < 262144) {   // weight convert + bias sums
        float4 a; us4 o;
        a = ((const float4*)wihf)[v];
        o.x = f2b(a.x); o.y = f2b(a.y); o.z = f2b(a.z); o.w = f2b(a.w);
        *(us4*)(wih + (size_t)v * 4) = o;
        a = ((const float4*)whhf)[v];
        o.x = f2b(a.x); o.y = f2b(a.y); o.z = f2b(a.z); o.w = f2b(a.w);
        *(us4*)(whh + (size_t)v * 4) = o;
        a = ((const float4*)wihb)[v];
        o.x = f2b(a.x); o.y = f2b(a.y); o.z = f2b(a.z); o.w = f2b(a.w);
        *(us4*)(wih + 1048576 + (size_t)v * 4) = o;
        a = ((const float4*)whhb)[v];
        o.x = f2b(a.x); o.y = f2b(a.y); o.z = f2b(a.z); o.w = f2b(a.w);
        *(us4*)(whh + 1048576 + (size_t)v * 4) = o;
        if (v < 2048)      bias[v] = bihf[v] + bhhf[v];
        else if (v < 4096) bias[v] = bihb[v - 2048] + bhhb[v - 2048];
    }
}

// ---------------- persistent bidirectional LSTM, tag-in-data self-sync ----------------
// grid 64: dir = bx>>5, wg = bx&31 owns hidden cols [wg*16, wg*16+16). 1 WG/CU.
// h is exchanged as 8B chunks {2×bf16 data | uint tag = te} stored with ONE atomic
// dwordx2 store. No flags, no producer drain, no poll: the consumer issues all 32
// gather loads at step start (addresses depend only on t), overlaps them with the
// x-MFMA and xbuf staging, then tag-checks in registers and re-loads only stale
// chunks. Unwritten memory is 0xFF-memset (tag 0xFFFFFFFF != any te). Barriers per
// step: B1 (hbuf) + B2 (gbuf) only; B3 deleted (xbuf^1 written before B1).
__global__ __launch_bounds__(256, 1) void lstm_rec(const unsigned short* __restrict__ whh,
                                                   const unsigned short* __restrict__ wih,
                                                   const unsigned short* __restrict__ xb,
                                                   const float* __restrict__ bias,
                                                   ull* __restrict__ h8)
{
    __shared__ unsigned short xbuf[2][32][520];   // x_t staging, double-buffered
    __shared__ unsigned short hbuf[32][520];      // h_{t-1} staging (data only, tags stripped)
    __shared__ float gbuf[4][32][16];             // gate pre-activations

    const int bx = blockIdx.x;
    const int dir = bx >> 5;
    const int wg = bx & 31;
    const int js = wg * 16;
    const int tid = threadIdx.x;
    const int wave = tid >> 6, lane = tid & 63;
    const int quad = lane >> 4, r16 = lane & 15;
    const int colw = wave * 512 + js + r16;       // gate-row in whh/wih

    // B-fragments: this WG's w_hh and w_ih slices, in registers
    bf16x8 wfr[16], xfr[16];
    {
        const unsigned short* wrow = whh + (size_t)dir * GG * HH + (size_t)colw * 512;
        const unsigned short* xrow = wih + (size_t)dir * GG * EE + (size_t)colw * 512;
#pragma unroll
        for (int kc = 0; kc < 16; ++kc) {
            wfr[kc] = *(const bf16x8*)(wrow + kc * 32 + quad * 8);
            xfr[kc] = *(const bf16x8*)(xrow + kc * 32 + quad * 8);
        }
    }
    const float bsw = bias[dir * GG + colw];

    // cell state in registers: thread owns (b = tid>>3, j = js + 2*(tid&7) + {0,1})
    const int cb = tid >> 3, cj = (tid & 7) * 2;
    float cr0 = 0.f, cr1 = 0.f;

    ull* hd8 = h8 + (size_t)dir * TT * BB * 256;  // [te][b][256 chunks]
    const ull* xbsrc = (const ull*)xb;            // 128 ull per 512-col row

    // prologue: stage x for the first step into xbuf[0]
    {
        const int te0 = dir ? (TT - 1) : 0;
#pragma unroll
        for (int i = 0; i < 16; ++i) {
            int v = tid + i * 256;
            int row = v >> 7, wi = v & 127;
            ull xv = xbsrc[((size_t)(row << 8) + te0) * 128 + wi];
            *(ull*)&xbuf[0][row][wi * 4] = xv;
        }
    }
    __syncthreads();
    int buf = 0;

    for (int t = 0; t < TT; ++t) {
        const int te = dir ? (TT - 1 - t) : t;

        // ---- 1. issue all 32 tagged gather loads for h(t-1) (self-synchronizing) ----
        ull hv[32];
        unsigned int tagexp = 0;
        const ull* hsrc8 = hd8;   // overwritten below when valid
        if (t > 0) {
            const int tp = dir ? (te + 1) : (te - 1);
            tagexp = (unsigned int)tp;
            hsrc8 = hd8 + (size_t)tp * BB * 256;
#pragma unroll
            for (int i = 0; i < 32; ++i)
                hv[i] = AGLD(&hsrc8[tid + i * 256]);
        }

        // ---- 2. issue next step's x loads ----
        ull xpre[16];
        if (t + 1 < TT) {
            const int tn = dir ? (te - 1) : (te + 1);
#pragma unroll
            for (int i = 0; i < 16; ++i) {
                int v = tid + i * 256;
                int row = v >> 7, wi = v & 127;
                xpre[i] = xbsrc[((size_t)(row << 8) + tn) * 128 + wi];
            }
        }

        // ---- 3. x-MFMA: acc := x_t @ Wih^T (LDS-only; overlaps in-flight loads) ----
        f32x4 alo = {0.f, 0.f, 0.f, 0.f}, ahi = {0.f, 0.f, 0.f, 0.f};
#pragma unroll
        for (int kc = 0; kc < 16; ++kc) {
            const int ko = kc * 32 + quad * 8;
            bf16x8 aflo = *(const bf16x8*)&xbuf[buf][r16][ko];
            bf16x8 afhi = *(const bf16x8*)&xbuf[buf][16 + r16][ko];
            alo = __builtin_amdgcn_mfma_f32_16x16x32_bf16(aflo, xfr[kc], alo, 0, 0, 0);
            ahi = __builtin_amdgcn_mfma_f32_16x16x32_bf16(afhi, xfr[kc], ahi, 0, 0, 0);
        }

        // ---- 4. write next x into the other xbuf (ordered by B1 for next step) ----
        if (t + 1 < TT) {
#pragma unroll
            for (int i = 0; i < 16; ++i) {
                int v = tid + i * 256;
                *(ull*)&xbuf[buf ^ 1][v >> 7][(v & 127) * 4] = xpre[i];
            }
        }

        // ---- 5. tag-check gather; re-load only stale chunks; stage into hbuf ----
        if (t > 0) {
            for (;;) {
                unsigned int stale = 0u;
#pragma unroll
                for (int i = 0; i < 32; ++i)
                    stale |= ((unsigned int)(hv[i] >> 32) != tagexp) ? (1u << i) : 0u;
                if (__ballot(stale != 0u) == 0ull) break;
#pragma unroll
                for (int i = 0; i < 32; ++i)
                    if (stale & (1u << i))
                        hv[i] = AGLD(&hsrc8[tid + i * 256]);
            }
#pragma unroll
            for (int i = 0; i < 32; ++i)
                *(unsigned int*)&hbuf[i][tid * 2] = (unsigned int)hv[i];
        }
        __syncthreads();   // B1: hbuf ready (and xbuf^1 published for next step)

        // ---- 6. h-MFMA ----
        if (t > 0) {
#pragma unroll
            for (int kc = 0; kc < 16; ++kc) {
                const int ko = kc * 32 + quad * 8;
                bf16x8 aflo = *(const bf16x8*)&hbuf[r16][ko];
                bf16x8 afhi = *(const bf16x8*)&hbuf[16 + r16][ko];
                alo = __builtin_amdgcn_mfma_f32_16x16x32_bf16(aflo, wfr[kc], alo, 0, 0, 0);
                ahi = __builtin_amdgcn_mfma_f32_16x16x32_bf16(afhi, wfr[kc], ahi, 0, 0, 0);
            }
        }

#pragma unroll
        for (int r = 0; r < 4; ++r) {
            gbuf[wave][quad * 4 + r][r16]      = alo[r] + bsw;
            gbuf[wave][16 + quad * 4 + r][r16] = ahi[r] + bsw;
        }
        __syncthreads();   // B2: gbuf ready (and all hbuf reads done)

        // ---- 7. nonlinearity + tagged fire-and-forget h store ----
        {
            float2 iv = *(const float2*)&gbuf[0][cb][cj];
            float2 fv = *(const float2*)&gbuf[1][cb][cj];
            float2 gv = *(const float2*)&gbuf[2][cb][cj];
            float2 ov = *(const float2*)&gbuf[3][cb][cj];
            cr0 = sigm(fv.x) * cr0 + sigm(iv.x) * tanh_f(gv.x);
            cr1 = sigm(fv.y) * cr1 + sigm(iv.y) * tanh_f(gv.y);
            float h0 = sigm(ov.x) * tanh_f(cr0);
            float h1 = sigm(ov.y) * tanh_f(cr1);
            unsigned int packed = (unsigned int)f2b(h0) | ((unsigned int)f2b(h1) << 16);
            ull out = (ull)packed | ((ull)(unsigned int)te << 32);
            ASTD(&hd8[(size_t)te * BB * 256 + cb * 256 + ((js + cj) >> 1)], out);
        }
        buf ^= 1;
    }
}

// ---------------- classifier: logits = [hf|hb] @ cls_w^T + cls_b ----------------
__global__ __launch_bounds__(256) void logits_k(const ull* __restrict__ h8,
                                                const float* __restrict__ clsw,
                                                const float* __restrict__ clsb,
                                                float* __restrict__ logits)
{
    const int tid = threadIdx.x;
    const int wave = tid >> 6, lane = tid & 63;
    const int wgid = blockIdx.x * 4 + wave;    // 0..1023

    unsigned int wreg[9][8];
#pragma unroll
    for (int c = 0; c < 9; ++c)
#pragma unroll
        for (int q = 0; q < 8; ++q) {
            float w0 = clsw[c * 1024 + (2 * q) * 64 + lane];
            float w1 = clsw[c * 1024 + (2 * q + 1) * 64 + lane];
            wreg[c][q] = (unsigned int)f2b(w0) | ((unsigned int)f2b(w1) << 16);
        }

    for (int i = 0; i < 8; ++i) {
        int m = wgid * 8 + i;                  // m = b*256 + t
        int b = m >> 8, t = m & 255;
        const ull* hf8 = h8 + ((size_t)t * BB + b) * 256;
        const ull* hb8 = h8 + (size_t)TT * BB * 256 + ((size_t)t * BB + b) * 256;
        float acc[9];
#pragma unroll
        for (int c = 0; c < 9; ++c) acc[c] = 0.f;
#pragma unroll
        for (int u = 0; u < 16; ++u) {
            const ull* s8 = (u < 8) ? hf8 : hb8;
            int cc = (u & 7) * 64 + lane;      // col within direction, 0..511
            ull ch = s8[cc >> 1];
            unsigned int lo = (unsigned int)ch;
            float hv = b2f((unsigned short)(lo >> ((cc & 1) * 16)));
#pragma unroll
            for (int c = 0; c < 9; ++c) {
                unsigned short wv = (u & 1) ? (unsigned short)(wreg[c][u >> 1] >> 16)
                                            : (unsigned short)(wreg[c][u >> 1] & 0xFFFFu);
                acc[c] += hv * b2f(wv);
            }
        }
#pragma unroll
        for (int c = 0; c < 9; ++c) {
            float s = acc[c];
            for (int off = 32; off > 0; off >>= 1) s += __shfl_down(s, off);
            if (lane == 0) logits[(size_t)m * 9 + c] = s + clsb[c];
        }
    }
}

// ---------------- CRF log-likelihood per sequence ----------------
__global__ void crf_k(const float* __restrict__ logits, const int* __restrict__ label,
                      const float* __restrict__ startp, const float* __restrict__ endp,
                      const float* __restrict__ trans, float* __restrict__ llh)
{
    const int b = blockIdx.x;
    const int lane = threadIdx.x;   // 64
    __shared__ float tr[81];
    __shared__ float alpha[9];
    __shared__ int tags[TT];
    for (int v = lane; v < 81; v += 64) tr[v] = trans[v];
    for (int v = lane; v < TT; v += 64) tags[v] = label[b * TT + v];
    __syncthreads();
    const float* lg = logits + (size_t)b * TT * 9;

    float part = 0.f; int mcnt = 0;
    for (int t = lane; t < TT; t += 64) {
        int tg = tags[t];
        bool m = tg > -1;
        if (m) mcnt++;
        if (t == 0)      part += startp[tg] + lg[tg];
        else if (m)      part += lg[t * 9 + tg] + tr[tags[t - 1] * 9 + tg];
    }
    for (int off = 32; off > 0; off >>= 1) {
        part += __shfl_down(part, off);
        mcnt += __shfl_down(mcnt, off);
    }
    part = __shfl(part, 0);
    mcnt = __shfl(mcnt, 0);
    float num = part + endp[tags[mcnt - 1]];

    if (lane < 9) alpha[lane] = startp[lane] + lg[lane];
    __syncthreads();
    for (int t = 1; t < TT; ++t) {
        float nxt = 0.f;
        if (lane < 9) {
            float mx = -1e30f;
#pragma unroll
            for (int c1 = 0; c1 < 9; ++c1) mx = fmaxf(mx, alpha[c1] + tr[c1 * 9 + lane]);
            float s = 0.f;
#pragma unroll
            for (int c1 = 0; c1 < 9; ++c1) s += __expf(alpha[c1] + tr[c1 * 9 + lane] - mx);
            nxt = mx + __logf(s) + lg[t * 9 + lane];
            if (tags[t] <= -1) nxt = alpha[lane];
        }
        __syncthreads();
        if (lane < 9) alpha[lane] = nxt;
        __syncthreads();
    }
    if (lane == 0) {
        float mx = -1e30f;
#pragma unroll
        for (int c = 0; c < 9; ++c) mx = fmaxf(mx, alpha[c] + endp[c]);
        float s = 0.f;
#pragma unroll
        for (int c = 0; c < 9; ++c) s += __expf(alpha[c] + endp[c] - mx);
        llh[b] = num - (mx + __logf(s));
    }
}

__global__ void fin_k(const float* __restrict__ llh, float* __restrict__ out)
{
    int lane = threadIdx.x;
    float v = (lane < 32) ? llh[lane] : 0.f;
    for (int off = 32; off > 0; off >>= 1) v += __shfl_down(v, off);
    if (lane == 0) out[0] = -v * (1.f / 32.f);
}

// ---------------- launch ----------------
extern "C" void kernel_launch(void* const* d_in, const int* in_sizes, int n_in,
                              void* d_out, int out_size, void* d_ws, size_t ws_size,
                              hipStream_t stream)
{
    const int*   ids   = (const int*)  d_in[0];
    const int*   label = (const int*)  d_in[1];
    const float* emb   = (const float*)d_in[2];
    const float* wihf  = (const float*)d_in[3];
    const float* whhf  = (const float*)d_in[4];
    const float* bihf  = (const float*)d_in[5];
    const float* bhhf  = (const float*)d_in[6];
    const float* wihb  = (const float*)d_in[7];
    const float* whhb  = (const float*)d_in[8];
    const float* bihb  = (const float*)d_in[9];
    const float* bhhb  = (const float*)d_in[10];
    const float* clsw  = (const float*)d_in[11];
    const float* clsb  = (const float*)d_in[12];
    const float* stp   = (const float*)d_in[13];
    const float* enp   = (const float*)d_in[14];
    const float* trp   = (const float*)d_in[15];

    char* ws = (char*)d_ws;
    unsigned short* xb   = (unsigned short*)(ws + 0);           //  8 MB  [8192][512] bf16
    unsigned short* wih  = (unsigned short*)(ws + 8388608);     //  4 MB  [2][2048][512]
    unsigned short* whh  = (unsigned short*)(ws + 12582912);    //  4 MB  [2][2048][512]
    float*          bias = (float*)(ws + 16777216);             // 16 KB  [2][2048]
    ull*            hall8= (ull*)(ws + 16793600);               // 32 MB  [2][256][32][256] tagged
    float*          lgt  = (float*)(ws + 50348032);             // 288 KB [8192][9]
    float*          llh  = (float*)(ws + 50642944);             // 128 B

    hipMemsetAsync(hall8, 0xFF, 33554432, stream);   // tag init: 0xFFFFFFFF != any te
    prep_embed_k<<<4096, 256, 0, stream>>>(ids, emb, wihf, whhf, wihb, whhb,
                                           bihf, bhhf, bihb, bhhb, xb, wih, whh, bias);
    lstm_rec<<<64, 256, 0, stream>>>(whh, wih, xb, bias, hall8);
    logits_k<<<256, 256, 0, stream>>>(hall8, clsw, clsb, lgt);
    crf_k<<<32, 64, 0, stream>>>(lgt, label, stp, enp, trp, llh);
    fin_k<<<1, 64, 0, stream>>>(llh, (float*)d_out);
}